// Round 1
// baseline (105.830 us; speedup 1.0000x reference)
//
#include <hip/hip_runtime.h>
#include <math.h>
#include <stdint.h>

// n=256 samples, d=64, fp32 in/out. J-path bf16 MFMA.
//   K[m][l] = (1-h^2)[m] W1[m][l];  sKT[l][m] = K[m][l] (bf16), row 64 = h
//   W2sB[i][j][m] = bf16(W2[(i,j)][m] + W2[(j,i)][m])  (symmetric in i,j)
//   slab-frag af[t] (rows of W2s_i) and sKT-frag bf[t] are BOTH valid as A or B:
//     C1 = mfma(A=af[tr], B=bf[tc]) -> Ji[j][l]       (j=row, l=col)
//     C2 = mfma(A=bf[tr], B=af[tc]) -> Ji[l][j]       at the SAME (lane,reg)!
//   => q[l] += v_i * v_j * C1^2 * C2 fully in-register; no LDS transpose,
//      no barriers in the i-loop.
// v2: 512 threads/block (8 waves, 2/SIMD) — kernel was latency-bound at
//     1 wave/SIMD (Occupancy 9.6%, MfmaUtil 15%, VALUBusy 21%). Each wave
//     owns 8 i's. h/out phases use 8 lanes/row + shfl reduce; Jacobi is
//     double-buffered (1 barrier/iter) with a 2-way-bank column mapping.

typedef short short8 __attribute__((ext_vector_type(8)));
typedef float f32x4 __attribute__((ext_vector_type(4)));

__device__ __forceinline__ unsigned short f2bf(float f) {
  unsigned int u = __builtin_bit_cast(unsigned int, f);
  u += 0x7fffu + ((u >> 16) & 1u);
  return (unsigned short)(u >> 16);
}

__device__ __forceinline__ short8 as_short8(uint4 u) {
  union { uint4 a; short8 b; } cv; cv.a = u; return cv.b;
}

__global__ __launch_bounds__(256) void prep_w2s_kernel(const float* __restrict__ W2,
                                                       unsigned short* __restrict__ W2sB) {
  int g = blockIdx.x * 256 + threadIdx.x;      // each thread: 8 consecutive m
  int i = g >> 9, j = (g >> 3) & 63, m8 = (g & 7) << 3;
  const float* pa = &W2[((((i << 6) + j) << 6) + m8)];
  const float* pb = &W2[((((j << 6) + i) << 6) + m8)];
  float4 a0 = *(const float4*)pa, a1 = *(const float4*)(pa + 4);
  float4 b0 = *(const float4*)pb, b1 = *(const float4*)(pb + 4);
  short8 r;
  r[0] = (short)f2bf(a0.x + b0.x); r[1] = (short)f2bf(a0.y + b0.y);
  r[2] = (short)f2bf(a0.z + b0.z); r[3] = (short)f2bf(a0.w + b0.w);
  r[4] = (short)f2bf(a1.x + b1.x); r[5] = (short)f2bf(a1.y + b1.y);
  r[6] = (short)f2bf(a1.z + b1.z); r[7] = (short)f2bf(a1.w + b1.w);
  *(short8*)&W2sB[(size_t)g << 3] = r;
}

__global__ __launch_bounds__(512, 2) void conn_kernel(
    const float* __restrict__ x, const float* __restrict__ v,
    const float* __restrict__ W1, const float* __restrict__ b1,
    const float* __restrict__ b2, const float* __restrict__ W3,
    const unsigned short* __restrict__ W2sB, float* __restrict__ out) {
  __shared__ __align__(16) unsigned short sKT[80 * 80];  // rows 0-63 = K^T, 64 = h, 65-79 = 0
  __shared__ __align__(16) float sg[64 * 68];            // g, stride 68 (f32x4-aligned stores)
  __shared__ float spq[8][64];
  __shared__ __align__(16) float sh[64], sv[64], sx[64], sq[64];
  __shared__ __align__(16) float sz2[2][64];

  const int n = blockIdx.x, t = threadIdx.x;
  const int wv = t >> 6, lane = t & 63, ln15 = lane & 15, quad = lane >> 4;
  const int o8 = t >> 3, s8 = t & 7;

  if (t < 64) sx[t] = x[(n << 6) + t];
  else if (t < 128) sv[t - 64] = v[(n << 6) + (t - 64)];
  for (int e = t; e < 1280; e += 512) sKT[5120 + e] = 0;  // zero rows 64..79
  __syncthreads();

  // h[o] = tanh(b1[o] + sum_l sx[l] W1[o][l]); 8 lanes per output, shfl reduce
  {
    const float* w1r = &W1[(o8 << 6) + (s8 << 3)];
    float4 wa = *(const float4*)w1r, wb = *(const float4*)(w1r + 4);
    float4 xa = *(const float4*)&sx[s8 << 3], xb = *(const float4*)&sx[(s8 << 3) + 4];
    float acc = wa.x * xa.x + wa.y * xa.y + wa.z * xa.z + wa.w * xa.w
              + wb.x * xb.x + wb.y * xb.y + wb.z * xb.z + wb.w * xb.w;
    acc += __shfl_xor(acc, 1);
    acc += __shfl_xor(acc, 2);
    acc += __shfl_xor(acc, 4);
    if (s8 == 0) sh[o8] = tanhf(acc + b1[o8]);
  }
  __syncthreads();

  for (int e = t; e < 4096; e += 512) {
    int m = e & 63, l = e >> 6;
    float hm = sh[m];
    sKT[l * 80 + m] = f2bf((1.f - hm * hm) * W1[(m << 6) + l]);
  }
  if (t < 64) sKT[64 * 80 + t] = f2bf(sh[t]);
  __syncthreads();

  // sKT frags: tiles 0..3 dual-use (A for C2 row-tile / B for C1 col-tile), tile 4 = ext (h)
  short8 bf[5][2];
  #pragma unroll
  for (int tc = 0; tc < 5; ++tc)
    #pragma unroll
    for (int ks = 0; ks < 2; ++ks)
      bf[tc][ks] = *(const short8*)&sKT[(tc * 16 + ln15) * 80 + ks * 32 + quad * 8];

  f32x4 svj[4];
  #pragma unroll
  for (int tr = 0; tr < 4; ++tr) svj[tr] = *(const f32x4*)&sv[tr * 16 + quad * 4];

  float qacc[4] = {0.f, 0.f, 0.f, 0.f};

  // Wave wv owns i in [8*wv, 8*wv+8). Slab frags: dual-use A(C1)/B(C2).
  const int foff = (ln15 << 6) + quad * 8;
  const unsigned short* sbase = W2sB + ((size_t)(8 * wv) << 12);

  uint4 af[4][2], afn[4][2];
  #pragma unroll
  for (int tc = 0; tc < 4; ++tc) {
    af[tc][0] = *(const uint4*)(sbase + (tc << 10) + foff);
    af[tc][1] = *(const uint4*)(sbase + (tc << 10) + foff + 32);
  }

  for (int ii = 0; ii < 8; ++ii) {
    const unsigned short* spn = W2sB + ((size_t)(8 * wv + ((ii + 1) & 7)) << 12);
    #pragma unroll
    for (int tc = 0; tc < 4; ++tc) {
      afn[tc][0] = *(const uint4*)(spn + (tc << 10) + foff);
      afn[tc][1] = *(const uint4*)(spn + (tc << 10) + foff + 32);
    }
    const int i = 8 * wv + ii;
    const float vi = sv[i];

    #pragma unroll
    for (int tr = 0; tr < 4; ++tr) {
      short8 a0 = as_short8(af[tr][0]), a1 = as_short8(af[tr][1]);
      f32x4 c1[4], c2[4], ce;
      #pragma unroll
      for (int tc = 0; tc < 4; ++tc) {
        f32x4 z4 = {0.f, 0.f, 0.f, 0.f};
        f32x4 u = __builtin_amdgcn_mfma_f32_16x16x32_bf16(a0, bf[tc][0], z4, 0, 0, 0);
        c1[tc]  = __builtin_amdgcn_mfma_f32_16x16x32_bf16(a1, bf[tc][1], u, 0, 0, 0);
        f32x4 w = __builtin_amdgcn_mfma_f32_16x16x32_bf16(bf[tr][0], as_short8(af[tc][0]), z4, 0, 0, 0);
        c2[tc]  = __builtin_amdgcn_mfma_f32_16x16x32_bf16(bf[tr][1], as_short8(af[tc][1]), w, 0, 0, 0);
      }
      {
        f32x4 z4 = {0.f, 0.f, 0.f, 0.f};
        f32x4 u = __builtin_amdgcn_mfma_f32_16x16x32_bf16(a0, bf[4][0], z4, 0, 0, 0);
        ce      = __builtin_amdgcn_mfma_f32_16x16x32_bf16(a1, bf[4][1], u, 0, 0, 0);
      }
      if (ln15 == 0)  // g[i][j], j = 16*tr + 4*quad + r
        *(f32x4*)&sg[i * 68 + tr * 16 + quad * 4] = ce;

      #pragma unroll
      for (int tc = 0; tc < 4; ++tc) {
        float s = 0.f;
        #pragma unroll
        for (int r = 0; r < 4; ++r) {
          float a = c1[tc][r];
          s = fmaf(a * a * c2[tc][r], svj[tr][r], s);
        }
        qacc[tc] = fmaf(s, vi, qacc[tc]);
      }
    }
    #pragma unroll
    for (int tc = 0; tc < 4; ++tc) { af[tc][0] = afn[tc][0]; af[tc][1] = afn[tc][1]; }
  }

  // reduce qacc over quads (rows j), publish per-wave partial q
  #pragma unroll
  for (int tc = 0; tc < 4; ++tc) {
    float s = qacc[tc];
    s += __shfl_xor(s, 16, 64);
    s += __shfl_xor(s, 32, 64);
    if (quad == 0) spq[wv][tc * 16 + ln15] = s;
  }
  __syncthreads();  // first block-wide sync since setup

  for (int e = t; e < 4096; e += 512) {   // g += b2 + b2^T
    int r = e >> 6, c = e & 63;
    sg[r * 68 + c] += b2[(r << 6) + c] + b2[(c << 6) + r];
  }
  __syncthreads();

  if (t < 64) {
    float s = spq[0][t] + spq[1][t] + spq[2][t] + spq[3][t]
            + spq[4][t] + spq[5][t] + spq[6][t] + spq[7][t];
    sq[t] = s;
    sz2[0][t] = s / sg[t * 68 + t];   // Jacobi init
  }
  __syncthreads();

  // Jacobi: z' = z + (q - g z)/diag; 8 lanes/row, double-buffered (1 barrier/iter)
  {
    const int row = o8;
    const float* grow = &sg[row * 68];
    const float dinv = 1.f / grow[row];
    const float qr = sq[row];
    int pb = 0;
    for (int it = 0; it < 20; ++it) {
      float p = 0.f;
      #pragma unroll
      for (int cc = 0; cc < 8; ++cc) {
        int c = (cc << 3) + s8;      // bank = (4*row + 8*cc + s8) % 32 -> 2-way (free)
        p += grow[c] * sz2[pb][c];
      }
      p += __shfl_xor(p, 1);
      p += __shfl_xor(p, 2);
      p += __shfl_xor(p, 4);
      if (s8 == 0) sz2[pb ^ 1][row] = sz2[pb][row] + (qr - p) * dinv;
      __syncthreads();
      pb ^= 1;
    }
  }
  // 20 iters (even) -> final z in sz2[0]

  // out[o] = sum_c v[c] W3[o][c] + 0.5 * sum_c z[c] W3[o][64+c]; 8 lanes/row
  {
    const float* w3r = &W3[o8 << 7];
    float4 wva = *(const float4*)&w3r[s8 << 3];
    float4 wvb = *(const float4*)&w3r[(s8 << 3) + 4];
    float4 wda = *(const float4*)&w3r[64 + (s8 << 3)];
    float4 wdb = *(const float4*)&w3r[64 + (s8 << 3) + 4];
    float4 va = *(const float4*)&sv[s8 << 3], vb = *(const float4*)&sv[(s8 << 3) + 4];
    float4 za = *(const float4*)&sz2[0][s8 << 3], zb = *(const float4*)&sz2[0][(s8 << 3) + 4];
    float acc = wva.x * va.x + wva.y * va.y + wva.z * va.z + wva.w * va.w
              + wvb.x * vb.x + wvb.y * vb.y + wvb.z * vb.z + wvb.w * vb.w
              + 0.5f * (wda.x * za.x + wda.y * za.y + wda.z * za.z + wda.w * za.w
                      + wdb.x * zb.x + wdb.y * zb.y + wdb.z * zb.z + wdb.w * zb.w);
    acc += __shfl_xor(acc, 1);
    acc += __shfl_xor(acc, 2);
    acc += __shfl_xor(acc, 4);
    if (s8 == 0) out[(n << 6) + o8] = acc;
  }
}

extern "C" void kernel_launch(void* const* d_in, const int* in_sizes, int n_in,
                              void* d_out, int out_size, void* d_ws, size_t ws_size,
                              hipStream_t stream) {
  (void)in_sizes; (void)n_in; (void)out_size; (void)ws_size;
  const float* x  = (const float*)d_in[1];
  const float* v  = (const float*)d_in[2];
  const float* W1 = (const float*)d_in[3];
  const float* b1 = (const float*)d_in[4];
  const float* W2 = (const float*)d_in[5];
  const float* b2 = (const float*)d_in[6];
  const float* W3 = (const float*)d_in[7];
  unsigned short* W2sB = (unsigned short*)d_ws;  // 64*64*64 bf16 = 512 KB

  hipLaunchKernelGGL(prep_w2s_kernel, dim3(128), dim3(256), 0, stream, W2, W2sB);
  hipLaunchKernelGGL(conn_kernel, dim3(256), dim3(512), 0, stream,
                     x, v, W1, b1, b2, W3, W2sB, (float*)d_out);
}

// Round 2
// 105.571 us; speedup vs baseline: 1.0025x; 1.0025x over previous
//
#include <hip/hip_runtime.h>
#include <math.h>
#include <stdint.h>

// n=256 samples, d=64, fp32 in/out. J-path bf16 MFMA.
//   K[m][l] = (1-h^2)[m] W1[m][l];  sKT[l][m] = K[m][l] (bf16), row 64 = h
//   W2sB[i][j][m] = bf16(W2[(i,j)][m] + W2[(j,i)][m])  (symmetric in i,j)
//   slab-frag af[t] (rows of W2s_i) and sKT-frag bf[t] are BOTH valid as A or B:
//     C1 = mfma(A=af[tr], B=bf[tc]) -> Ji[j][l]       (j=row, l=col)
//     C2 = mfma(A=bf[tr], B=af[tc]) -> Ji[l][j]       at the SAME (lane,reg)!
//   => q[l] += v_i * v_j * C1^2 * C2 fully in-register; no LDS transpose,
//      no barriers in the i-loop.
// v2: 512 threads/block (8 waves, 2/SIMD) — kernel was latency-bound at
//     1 wave/SIMD. h/out phases 8 lanes/row + shfl; Jacobi double-buffered.
// v3: __launch_bounds__(512) WITHOUT min-waves clause. v2's (512,2) capped
//     VGPR at 128 -> ~19 regs/thread spilled to scratch (WRITE_SIZE 64KB ->
//     9.8MB, FETCH +4.9MB) and the spill latency in the i-loop ate the
//     entire occupancy gain. 168 VGPR fits 2 waves/SIMD (step is at 256).

typedef short short8 __attribute__((ext_vector_type(8)));
typedef float f32x4 __attribute__((ext_vector_type(4)));

__device__ __forceinline__ unsigned short f2bf(float f) {
  unsigned int u = __builtin_bit_cast(unsigned int, f);
  u += 0x7fffu + ((u >> 16) & 1u);
  return (unsigned short)(u >> 16);
}

__device__ __forceinline__ short8 as_short8(uint4 u) {
  union { uint4 a; short8 b; } cv; cv.a = u; return cv.b;
}

__global__ __launch_bounds__(256) void prep_w2s_kernel(const float* __restrict__ W2,
                                                       unsigned short* __restrict__ W2sB) {
  int g = blockIdx.x * 256 + threadIdx.x;      // each thread: 8 consecutive m
  int i = g >> 9, j = (g >> 3) & 63, m8 = (g & 7) << 3;
  const float* pa = &W2[((((i << 6) + j) << 6) + m8)];
  const float* pb = &W2[((((j << 6) + i) << 6) + m8)];
  float4 a0 = *(const float4*)pa, a1 = *(const float4*)(pa + 4);
  float4 b0 = *(const float4*)pb, b1 = *(const float4*)(pb + 4);
  short8 r;
  r[0] = (short)f2bf(a0.x + b0.x); r[1] = (short)f2bf(a0.y + b0.y);
  r[2] = (short)f2bf(a0.z + b0.z); r[3] = (short)f2bf(a0.w + b0.w);
  r[4] = (short)f2bf(a1.x + b1.x); r[5] = (short)f2bf(a1.y + b1.y);
  r[6] = (short)f2bf(a1.z + b1.z); r[7] = (short)f2bf(a1.w + b1.w);
  *(short8*)&W2sB[(size_t)g << 3] = r;
}

__global__ __launch_bounds__(512) void conn_kernel(
    const float* __restrict__ x, const float* __restrict__ v,
    const float* __restrict__ W1, const float* __restrict__ b1,
    const float* __restrict__ b2, const float* __restrict__ W3,
    const unsigned short* __restrict__ W2sB, float* __restrict__ out) {
  __shared__ __align__(16) unsigned short sKT[80 * 80];  // rows 0-63 = K^T, 64 = h, 65-79 = 0
  __shared__ __align__(16) float sg[64 * 68];            // g, stride 68 (f32x4-aligned stores)
  __shared__ float spq[8][64];
  __shared__ __align__(16) float sh[64], sv[64], sx[64], sq[64];
  __shared__ __align__(16) float sz2[2][64];

  const int n = blockIdx.x, t = threadIdx.x;
  const int wv = t >> 6, lane = t & 63, ln15 = lane & 15, quad = lane >> 4;
  const int o8 = t >> 3, s8 = t & 7;

  if (t < 64) sx[t] = x[(n << 6) + t];
  else if (t < 128) sv[t - 64] = v[(n << 6) + (t - 64)];
  for (int e = t; e < 1280; e += 512) sKT[5120 + e] = 0;  // zero rows 64..79
  __syncthreads();

  // h[o] = tanh(b1[o] + sum_l sx[l] W1[o][l]); 8 lanes per output, shfl reduce
  {
    const float* w1r = &W1[(o8 << 6) + (s8 << 3)];
    float4 wa = *(const float4*)w1r, wb = *(const float4*)(w1r + 4);
    float4 xa = *(const float4*)&sx[s8 << 3], xb = *(const float4*)&sx[(s8 << 3) + 4];
    float acc = wa.x * xa.x + wa.y * xa.y + wa.z * xa.z + wa.w * xa.w
              + wb.x * xb.x + wb.y * xb.y + wb.z * xb.z + wb.w * xb.w;
    acc += __shfl_xor(acc, 1);
    acc += __shfl_xor(acc, 2);
    acc += __shfl_xor(acc, 4);
    if (s8 == 0) sh[o8] = tanhf(acc + b1[o8]);
  }
  __syncthreads();

  for (int e = t; e < 4096; e += 512) {
    int m = e & 63, l = e >> 6;
    float hm = sh[m];
    sKT[l * 80 + m] = f2bf((1.f - hm * hm) * W1[(m << 6) + l]);
  }
  if (t < 64) sKT[64 * 80 + t] = f2bf(sh[t]);
  __syncthreads();

  // sKT frags: tiles 0..3 dual-use (A for C2 row-tile / B for C1 col-tile), tile 4 = ext (h)
  short8 bf[5][2];
  #pragma unroll
  for (int tc = 0; tc < 5; ++tc)
    #pragma unroll
    for (int ks = 0; ks < 2; ++ks)
      bf[tc][ks] = *(const short8*)&sKT[(tc * 16 + ln15) * 80 + ks * 32 + quad * 8];

  f32x4 svj[4];
  #pragma unroll
  for (int tr = 0; tr < 4; ++tr) svj[tr] = *(const f32x4*)&sv[tr * 16 + quad * 4];

  float qacc[4] = {0.f, 0.f, 0.f, 0.f};

  // Wave wv owns i in [8*wv, 8*wv+8). Slab frags: dual-use A(C1)/B(C2).
  const int foff = (ln15 << 6) + quad * 8;
  const unsigned short* sbase = W2sB + ((size_t)(8 * wv) << 12);

  uint4 af[4][2], afn[4][2];
  #pragma unroll
  for (int tc = 0; tc < 4; ++tc) {
    af[tc][0] = *(const uint4*)(sbase + (tc << 10) + foff);
    af[tc][1] = *(const uint4*)(sbase + (tc << 10) + foff + 32);
  }

  for (int ii = 0; ii < 8; ++ii) {
    const unsigned short* spn = W2sB + ((size_t)(8 * wv + ((ii + 1) & 7)) << 12);
    #pragma unroll
    for (int tc = 0; tc < 4; ++tc) {
      afn[tc][0] = *(const uint4*)(spn + (tc << 10) + foff);
      afn[tc][1] = *(const uint4*)(spn + (tc << 10) + foff + 32);
    }
    const int i = 8 * wv + ii;
    const float vi = sv[i];

    #pragma unroll
    for (int tr = 0; tr < 4; ++tr) {
      short8 a0 = as_short8(af[tr][0]), a1 = as_short8(af[tr][1]);
      f32x4 c1[4], c2[4], ce;
      #pragma unroll
      for (int tc = 0; tc < 4; ++tc) {
        f32x4 z4 = {0.f, 0.f, 0.f, 0.f};
        f32x4 u = __builtin_amdgcn_mfma_f32_16x16x32_bf16(a0, bf[tc][0], z4, 0, 0, 0);
        c1[tc]  = __builtin_amdgcn_mfma_f32_16x16x32_bf16(a1, bf[tc][1], u, 0, 0, 0);
        f32x4 w = __builtin_amdgcn_mfma_f32_16x16x32_bf16(bf[tr][0], as_short8(af[tc][0]), z4, 0, 0, 0);
        c2[tc]  = __builtin_amdgcn_mfma_f32_16x16x32_bf16(bf[tr][1], as_short8(af[tc][1]), w, 0, 0, 0);
      }
      {
        f32x4 z4 = {0.f, 0.f, 0.f, 0.f};
        f32x4 u = __builtin_amdgcn_mfma_f32_16x16x32_bf16(a0, bf[4][0], z4, 0, 0, 0);
        ce      = __builtin_amdgcn_mfma_f32_16x16x32_bf16(a1, bf[4][1], u, 0, 0, 0);
      }
      if (ln15 == 0)  // g[i][j], j = 16*tr + 4*quad + r
        *(f32x4*)&sg[i * 68 + tr * 16 + quad * 4] = ce;

      #pragma unroll
      for (int tc = 0; tc < 4; ++tc) {
        float s = 0.f;
        #pragma unroll
        for (int r = 0; r < 4; ++r) {
          float a = c1[tc][r];
          s = fmaf(a * a * c2[tc][r], svj[tr][r], s);
        }
        qacc[tc] = fmaf(s, vi, qacc[tc]);
      }
    }
    #pragma unroll
    for (int tc = 0; tc < 4; ++tc) { af[tc][0] = afn[tc][0]; af[tc][1] = afn[tc][1]; }
  }

  // reduce qacc over quads (rows j), publish per-wave partial q
  #pragma unroll
  for (int tc = 0; tc < 4; ++tc) {
    float s = qacc[tc];
    s += __shfl_xor(s, 16, 64);
    s += __shfl_xor(s, 32, 64);
    if (quad == 0) spq[wv][tc * 16 + ln15] = s;
  }
  __syncthreads();  // first block-wide sync since setup

  for (int e = t; e < 4096; e += 512) {   // g += b2 + b2^T
    int r = e >> 6, c = e & 63;
    sg[r * 68 + c] += b2[(r << 6) + c] + b2[(c << 6) + r];
  }
  __syncthreads();

  if (t < 64) {
    float s = spq[0][t] + spq[1][t] + spq[2][t] + spq[3][t]
            + spq[4][t] + spq[5][t] + spq[6][t] + spq[7][t];
    sq[t] = s;
    sz2[0][t] = s / sg[t * 68 + t];   // Jacobi init
  }
  __syncthreads();

  // Jacobi: z' = z + (q - g z)/diag; 8 lanes/row, double-buffered (1 barrier/iter)
  {
    const int row = o8;
    const float* grow = &sg[row * 68];
    const float dinv = 1.f / grow[row];
    const float qr = sq[row];
    int pb = 0;
    for (int it = 0; it < 20; ++it) {
      float p = 0.f;
      #pragma unroll
      for (int cc = 0; cc < 8; ++cc) {
        int c = (cc << 3) + s8;      // bank = (4*row + 8*cc + s8) % 32 -> 2-way (free)
        p += grow[c] * sz2[pb][c];
      }
      p += __shfl_xor(p, 1);
      p += __shfl_xor(p, 2);
      p += __shfl_xor(p, 4);
      if (s8 == 0) sz2[pb ^ 1][row] = sz2[pb][row] + (qr - p) * dinv;
      __syncthreads();
      pb ^= 1;
    }
  }
  // 20 iters (even) -> final z in sz2[0]

  // out[o] = sum_c v[c] W3[o][c] + 0.5 * sum_c z[c] W3[o][64+c]; 8 lanes/row
  {
    const float* w3r = &W3[o8 << 7];
    float4 wva = *(const float4*)&w3r[s8 << 3];
    float4 wvb = *(const float4*)&w3r[(s8 << 3) + 4];
    float4 wda = *(const float4*)&w3r[64 + (s8 << 3)];
    float4 wdb = *(const float4*)&w3r[64 + (s8 << 3) + 4];
    float4 va = *(const float4*)&sv[s8 << 3], vb = *(const float4*)&sv[(s8 << 3) + 4];
    float4 za = *(const float4*)&sz2[0][s8 << 3], zb = *(const float4*)&sz2[0][(s8 << 3) + 4];
    float acc = wva.x * va.x + wva.y * va.y + wva.z * va.z + wva.w * va.w
              + wvb.x * vb.x + wvb.y * vb.y + wvb.z * vb.z + wvb.w * vb.w
              + 0.5f * (wda.x * za.x + wda.y * za.y + wda.z * za.z + wda.w * za.w
                      + wdb.x * zb.x + wdb.y * zb.y + wdb.z * zb.z + wdb.w * zb.w);
    acc += __shfl_xor(acc, 1);
    acc += __shfl_xor(acc, 2);
    acc += __shfl_xor(acc, 4);
    if (s8 == 0) out[(n << 6) + o8] = acc;
  }
}

extern "C" void kernel_launch(void* const* d_in, const int* in_sizes, int n_in,
                              void* d_out, int out_size, void* d_ws, size_t ws_size,
                              hipStream_t stream) {
  (void)in_sizes; (void)n_in; (void)out_size; (void)ws_size;
  const float* x  = (const float*)d_in[1];
  const float* v  = (const float*)d_in[2];
  const float* W1 = (const float*)d_in[3];
  const float* b1 = (const float*)d_in[4];
  const float* W2 = (const float*)d_in[5];
  const float* b2 = (const float*)d_in[6];
  const float* W3 = (const float*)d_in[7];
  unsigned short* W2sB = (unsigned short*)d_ws;  // 64*64*64 bf16 = 512 KB

  hipLaunchKernelGGL(prep_w2s_kernel, dim3(128), dim3(256), 0, stream, W2, W2sB);
  hipLaunchKernelGGL(conn_kernel, dim3(256), dim3(512), 0, stream,
                     x, v, W1, b1, b2, W3, W2sB, (float*)d_out);
}